// Round 14
// baseline (175.473 us; speedup 1.0000x reference)
//
#include <hip/hip_runtime.h>

#define BN_EPS 1e-3f

typedef __attribute__((ext_vector_type(8))) short bf16x8;
typedef __attribute__((ext_vector_type(4))) float f32x4;

__device__ inline unsigned short f2b(float f) {
    unsigned int u = __float_as_uint(f);
    unsigned int r = (u + 0x7fffu + ((u >> 16) & 1u)) >> 16;
    return (unsigned short)r;
}
__device__ inline float b2f(unsigned short h) {
    return __uint_as_float(((unsigned int)h) << 16);
}
// packed RNE f32x2 -> bf16x2 (lo = a, hi = b) — single VALU instruction
__device__ inline unsigned int pk2(float a, float b) {
    unsigned int r;
    asm("v_cvt_pk_bf16_f32 %0, %1, %2" : "=v"(r) : "v"(a), "v"(b));
    return r;
}
// packed bf16x2 dot: D = x.lo*w.lo + x.hi*w.hi + acc   (single VALU instr)
__device__ inline float dot2bf(unsigned int x, unsigned int w, float acc) {
    float r;
    asm("v_dot2_f32_bf16 %0, %1, %2, %3" : "=v"(r) : "v"(x), "v"(w), "v"(acc));
    return r;
}

// ---------------------------------------------------------------------------
// k_prep: Bt[n][k] = bf16 of (n<256 ? Wi[k][n] : Wr[k][n-256])   [320,256]
//         Wst[n][k] = bf16 of Ws[k][n]                            [144,64]
// ---------------------------------------------------------------------------
__global__ void k_prep(const float* __restrict__ Wi, const float* __restrict__ Wr,
                       const float* __restrict__ Ws,
                       unsigned short* __restrict__ Bt, unsigned short* __restrict__ Wst) {
    int t = blockIdx.x * 256 + threadIdx.x;
    if (t < 320 * 256) {
        int n = t >> 8, k = t & 255;
        float v = (n < 256) ? Wi[k * 256 + n] : Wr[k * 64 + (n - 256)];
        Bt[t] = f2b(v);
    } else {
        int t2 = t - 320 * 256;
        if (t2 < 144 * 64) {
            int n = t2 >> 6, k = t2 & 63;
            Wst[t2] = f2b(Ws[k * 144 + n]);
        }
    }
}

// ---------------------------------------------------------------------------
// gather8: 8 outputs from one 72-element (36-dword) run of packed bf16.
// ---------------------------------------------------------------------------
__device__ __forceinline__ void gather8(const int* dwp, const unsigned* pkA,
                                        const unsigned* pkB, float w0f, float w8f,
                                        float* res) {
#pragma unroll
    for (int ff = 0; ff < 8; ++ff) {
        const int e0 = ff * 9;
        float a;
        if ((ff & 1) == 0) {
            const int d0 = e0 >> 1;
            a = __uint_as_float(((unsigned)dwp[d0 + 4]) << 16) * w8f;
            a = dot2bf((unsigned)dwp[d0 + 0], pkA[0], a);
            a = dot2bf((unsigned)dwp[d0 + 1], pkA[1], a);
            a = dot2bf((unsigned)dwp[d0 + 2], pkA[2], a);
            a = dot2bf((unsigned)dwp[d0 + 3], pkA[3], a);
        } else {
            const int di = e0 >> 1;          // element e0 sits in hi half
            const int d1 = di + 1;
            a = __uint_as_float(((unsigned)dwp[di]) & 0xffff0000u) * w0f;
            a = dot2bf((unsigned)dwp[d1 + 0], pkB[0], a);
            a = dot2bf((unsigned)dwp[d1 + 1], pkB[1], a);
            a = dot2bf((unsigned)dwp[d1 + 2], pkB[2], a);
            a = dot2bf((unsigned)dwp[d1 + 3], pkB[3], a);
        }
        res[ff] = a;
    }
}

// ---------------------------------------------------------------------------
// k_fused: one block = one 16x8 output tile (halo 18x10 = 180 px). 8 waves.
//   XI region is XOR-SWIZZLED (T2/G4): u16 col ^= (row&7)<<3 — swizzles 16B
//   blocks within each row. Bijective (data cols < 256 = blocks 0..31),
//   preserves 16B alignment of b128 reads (cols multiple of 8) and 8B
//   alignment of staging uint2 writes. Applied at: staging-write, phase-1
//   A-read, epilogue xi-write, phase-3 gather-read. Breaks the c0(g)
//   4-bank-offset collision pattern in phase 3 (conflicts 3.77M -> ~1-2M).
//   phase 1: 6 chunks, in-place LDS, 2-ahead staging, ONE barrier per chunk.
//   phase 2: w = r @ Ws^T (+bs) on compacted 128 interior px -> WL (no swz).
//   phase 3: contiguous-run gather via v_dot2_f32_bf16.
// LDS (u16): XI 180x264 | RS 180x72 | WL 128x144  = 157,824 B -> 1 block/CU.
// ---------------------------------------------------------------------------
#define XIP 264
#define RS_OFF (180 * XIP)            // 47520
#define RSP 72
#define WL_OFF (RS_OFF + 180 * RSP)   // 60480
#define SMN (WL_OFF + 128 * 144)      // 78912 u16 = 157,824 B

// XI swizzled index: row, col in u16 units (col < 256 for all data accesses)
__device__ __forceinline__ int xidx(int row, int col) {
    return row * XIP + (col ^ ((row & 7) << 3));
}

__global__ __launch_bounds__(512, 2) void k_fused(
    const float* __restrict__ x, const unsigned short* __restrict__ Bt,
    const unsigned short* __restrict__ Wst,
    const float* __restrict__ bi, const float* __restrict__ br,
    const float* __restrict__ gamma, const float* __restrict__ beta,
    const float* __restrict__ mean, const float* __restrict__ var,
    const float* __restrict__ bs, float* __restrict__ out)
{
    __shared__ __attribute__((aligned(16))) unsigned short sm[SMN];
    const int tid = threadIdx.x;
    const int bx = blockIdx.x;
    const int w0 = (bx & 7) * 16;
    const int h0 = ((bx >> 3) & 15) * 8;
    const int bb = bx >> 7;

    const int wv = tid >> 6;
    const int lane = tid & 63;
    const int col = lane & 15;
    const int quad = lane >> 4;

    // ---- load per-wave constants & register-resident B fragments ----
    const float bi_v0 = bi[(2 * wv) * 16 + col];
    const float bi_v1 = bi[(2 * wv + 1) * 16 + col];
    const int dcl = (wv & 3) * 16 + col;       // r-column (valid when wv<4)
    const float brd = br[dcl];
    const float md  = mean[dcl];
    const float sc  = gamma[dcl] * rsqrtf(var[dcl] + BN_EPS);
    const float btv = beta[dcl];

    bf16x8 bx0[8], bx1[8], brr[8];
    {
        const unsigned short* p0 = &Bt[((2 * wv) * 16 + col) * 256];
        const unsigned short* p1 = &Bt[((2 * wv + 1) * 16 + col) * 256];
#pragma unroll
        for (int kc = 0; kc < 8; ++kc) {
            bx0[kc] = *(const bf16x8*)&p0[kc * 32 + quad * 8];
            bx1[kc] = *(const bf16x8*)&p1[kc * 32 + quad * 8];
        }
        if (wv < 4) {
            const unsigned short* pr = &Bt[((16 + wv) * 16 + col) * 256];
#pragma unroll
            for (int kc = 0; kc < 8; ++kc)
                brr[kc] = *(const bf16x8*)&pr[kc * 32 + quad * 8];
        }
    }

    // ---- staging helpers ----
    const int chq = (tid & 15) * 4;

    // prologue: stage chunks 0 and 1 (rows 0..63, all < 180)
#pragma unroll
    for (int pc = 0; pc < 2; ++pc) {
        float4 vcur[4];
        const int hp = pc * 32 + (tid >> 4);
        int r = hp / 18, cc = hp - r * 18;
        int gh = h0 - 1 + r, gw = w0 - 1 + cc;
        bool ok = ((unsigned)gh < 128u) && ((unsigned)gw < 128u);
        if (ok) {
            const float* src = x + (((long long)(bb * 128 + gh)) * 128 + gw) * 256 + chq;
#pragma unroll
            for (int j = 0; j < 4; ++j) vcur[j] = *(const float4*)&src[j * 64];
        } else {
#pragma unroll
            for (int j = 0; j < 4; ++j) vcur[j] = (float4){0.f, 0.f, 0.f, 0.f};
        }
#pragma unroll
        for (int j = 0; j < 4; ++j) {
            uint2 pk;
            pk.x = pk2(vcur[j].x, vcur[j].y);
            pk.y = pk2(vcur[j].z, vcur[j].w);
            *(uint2*)&sm[xidx(hp, chq + j * 64)] = pk;
        }
    }
    __syncthreads();

    // ---- chunk loop: ONE barrier per chunk, 2-ahead staging ----
    for (int c = 0; c < 6; ++c) {
        float4 vn[4];
        int hp_n = 200;
        if (c < 4) {
            hp_n = (c + 2) * 32 + (tid >> 4);
            int r = hp_n / 18, cc = hp_n - r * 18;
            int gh = h0 - 1 + r, gw = w0 - 1 + cc;
            bool ok = (hp_n < 180) && ((unsigned)gh < 128u) && ((unsigned)gw < 128u);
            if (ok) {
                const float* src = x + (((long long)(bb * 128 + gh)) * 128 + gw) * 256 + chq;
#pragma unroll
                for (int j = 0; j < 4; ++j) vn[j] = *(const float4*)&src[j * 64];
            } else {
#pragma unroll
                for (int j = 0; j < 4; ++j) vn[j] = (float4){0.f, 0.f, 0.f, 0.f};
            }
        }

        // MFMA chunk c (reads swizzled rows c)
        f32x4 a00 = {0.f,0.f,0.f,0.f}, a01 = a00, a10 = a00, a11 = a00;
        f32x4 ar0 = a00, ar1 = a00;
        {
            const int r0i = c * 32 + col;
            const int r1i = c * 32 + 16 + col;
#pragma unroll
            for (int kc = 0; kc < 8; ++kc) {
                const int kb = kc * 32 + quad * 8;
                bf16x8 a0 = *(const bf16x8*)&sm[xidx(r0i, kb)];
                bf16x8 a1 = *(const bf16x8*)&sm[xidx(r1i, kb)];
                a00 = __builtin_amdgcn_mfma_f32_16x16x32_bf16(a0, bx0[kc], a00, 0, 0, 0);
                a10 = __builtin_amdgcn_mfma_f32_16x16x32_bf16(a1, bx0[kc], a10, 0, 0, 0);
                a01 = __builtin_amdgcn_mfma_f32_16x16x32_bf16(a0, bx1[kc], a01, 0, 0, 0);
                a11 = __builtin_amdgcn_mfma_f32_16x16x32_bf16(a1, bx1[kc], a11, 0, 0, 0);
                if (wv < 4) {
                    ar0 = __builtin_amdgcn_mfma_f32_16x16x32_bf16(a0, brr[kc], ar0, 0, 0, 0);
                    ar1 = __builtin_amdgcn_mfma_f32_16x16x32_bf16(a1, brr[kc], ar1, 0, 0, 0);
                }
            }
        }
        __syncthreads();   // all waves' reads of rows_c done

        // epilogue chunk c: xi -> XI rows_c (in place, swizzled), r -> RS rows_c
        {
            const int n0 = (2 * wv) * 16 + col;
            const int n1 = (2 * wv + 1) * 16 + col;
            const int rb = c * 32 + quad * 4;
#pragma unroll
            for (int rg = 0; rg < 4; ++rg) {
                const int r0 = rb + rg, r1 = rb + 16 + rg;
                if (r0 < 180) {
                    const unsigned int u0 = pk2(a00[rg] + bi_v0, a01[rg] + bi_v1);
                    sm[xidx(r0, n0)] = (unsigned short)u0;
                    sm[xidx(r0, n1)] = (unsigned short)(u0 >> 16);
                }
                if (r1 < 180) {
                    const unsigned int u1 = pk2(a10[rg] + bi_v0, a11[rg] + bi_v1);
                    sm[xidx(r1, n0)] = (unsigned short)u1;
                    sm[xidx(r1, n1)] = (unsigned short)(u1 >> 16);
                }
            }
            if (wv < 4) {
#pragma unroll
                for (int rg = 0; rg < 4; ++rg) {
                    const int r0 = rb + rg, r1 = rb + 16 + rg;
                    if (r0 < 180) {
                        float v = (ar0[rg] + brd - md) * sc + btv;
                        sm[RS_OFF + r0 * RSP + dcl] = f2b(fmaxf(v, 0.f));
                    }
                    if (r1 < 180) {
                        float v = (ar1[rg] + brd - md) * sc + btv;
                        sm[RS_OFF + r1 * RSP + dcl] = f2b(fmaxf(v, 0.f));
                    }
                }
            }
        }

        // staged write chunk c+2 (rows disjoint; next read fenced by c+1 barrier)
        if (c < 4 && hp_n < 180) {
#pragma unroll
            for (int j = 0; j < 4; ++j) {
                uint2 pk;
                pk.x = pk2(vn[j].x, vn[j].y);
                pk.y = pk2(vn[j].z, vn[j].w);
                *(uint2*)&sm[xidx(hp_n, chq + j * 64)] = pk;
            }
        }
    }
    __syncthreads();   // epi(5) RS/XI writes complete before phase 2

    // ---- phase 2: w = r @ Wst^T (+bs); wave wv -> m-tile wv ----
    {
        f32x4 wacc[9];
#pragma unroll
        for (int j = 0; j < 9; ++j) wacc[j] = (f32x4){0.f, 0.f, 0.f, 0.f};
        const int arow = (19 + wv * 18 + col) * RSP;
#pragma unroll
        for (int kc = 0; kc < 2; ++kc) {
            const int kb = kc * 32 + quad * 8;
            bf16x8 ra = *(const bf16x8*)&sm[RS_OFF + arow + kb];
#pragma unroll
            for (int j = 0; j < 9; ++j) {
                bf16x8 wb = *(const bf16x8*)&Wst[(j * 16 + col) * 64 + kb];
                wacc[j] = __builtin_amdgcn_mfma_f32_16x16x32_bf16(ra, wb, wacc[j], 0, 0, 0);
            }
        }
        const int prow = wv * 16 + quad * 4;
#pragma unroll
        for (int j = 0; j < 8; j += 2) {
            const int na = j * 16 + col;
            const int nb = na + 16;
            const float bva = bs[na];
            const float bvb = bs[nb];
#pragma unroll
            for (int rg = 0; rg < 4; ++rg) {
                const unsigned int u = pk2(wacc[j][rg] + bva, wacc[j + 1][rg] + bvb);
                sm[WL_OFF + (prow + rg) * 144 + na] = (unsigned short)u;
                sm[WL_OFF + (prow + rg) * 144 + nb] = (unsigned short)(u >> 16);
            }
        }
        {
            const int n = 8 * 16 + col;
            const float bv = bs[n];
#pragma unroll
            for (int rg = 0; rg < 4; ++rg)
                sm[WL_OFF + (prow + rg) * 144 + n] = f2b(wacc[8][rg] + bv);
        }
    }
    __syncthreads();

    // ---- phase 3: gather via packed bf16 dot2 (swizzled XI reads) ----
    {
        const int g = tid & 15;
        const int pb = tid >> 4;               // 0..31

        const int idx0 = g * 144;
        const int kp0  = idx0 >> 8;
        const int c0   = idx0 & 255;           // multiple of 16
        int len1 = 256 - c0; if (len1 > 144) len1 = 144;
        const int kp1  = kp0 + 1;
        const int koff0 = (kp0 / 3) * 18 + (kp0 % 3);
        const int koff1 = (kp1 <= 8) ? ((kp1 / 3) * 18 + (kp1 % 3)) : 0;

#pragma unroll
        for (int jj = 0; jj < 4; ++jj) {
            const int p = pb + 32 * jj;        // interior px 0..127
            const int phb = (p >> 4) * 18 + (p & 15);
            const int row0 = phb + koff0;
            const int row1 = phb + koff1;

            // raw u16 weights -> packed bf16x2 operand sets
            unsigned wsv[9];
#pragma unroll
            for (int kk = 0; kk < 9; ++kk)
                wsv[kk] = sm[WL_OFF + p * 144 + g * 9 + kk];
            unsigned pkA[4], pkB[4];
#pragma unroll
            for (int k = 0; k < 4; ++k) {
                pkA[k] = (wsv[2 * k + 1] << 16) | wsv[2 * k];
                pkB[k] = (wsv[2 * k + 2] << 16) | wsv[2 * k + 1];
            }
            const float w0f = __uint_as_float(wsv[0] << 16);
            const float w8f = __uint_as_float(wsv[8] << 16);

            float res[16];
            {
                int4 xv[9];
#pragma unroll
                for (int i = 0; i < 9; ++i) {
                    const int e = i * 8;
                    const int addr = (e < len1) ? xidx(row0, c0 + e)
                                                : xidx(row1, e - len1);
                    xv[i] = *(const int4*)&sm[addr];
                }
                gather8((const int*)xv, pkA, pkB, w0f, w8f, res);
            }
            {
                int4 xv[9];
#pragma unroll
                for (int i = 9; i < 18; ++i) {
                    const int e = i * 8;
                    const int addr = (e < len1) ? xidx(row0, c0 + e)
                                                : xidx(row1, e - len1);
                    xv[i - 9] = *(const int4*)&sm[addr];
                }
                gather8((const int*)xv, pkA, pkB, w0f, w8f, res + 8);
            }

            const long long orow =
                (((long long)(bb * 128 + h0 + (p >> 4))) * 128 + (w0 + (p & 15))) * 256 + g * 16;
#pragma unroll
            for (int q = 0; q < 4; ++q) {
                float4 o = {res[q * 4 + 0], res[q * 4 + 1], res[q * 4 + 2], res[q * 4 + 3]};
                *(float4*)&out[orow + q * 4] = o;
            }
        }
    }
}

// ---------------------------------------------------------------------------
extern "C" void kernel_launch(void* const* d_in, const int* in_sizes, int n_in,
                              void* d_out, int out_size, void* d_ws, size_t ws_size,
                              hipStream_t stream) {
    const float* x     = (const float*)d_in[0];
    const float* Wr    = (const float*)d_in[1];
    const float* br    = (const float*)d_in[2];
    const float* gamma = (const float*)d_in[3];
    const float* beta  = (const float*)d_in[4];
    const float* mean  = (const float*)d_in[5];
    const float* var   = (const float*)d_in[6];
    const float* Ws    = (const float*)d_in[7];
    const float* bs    = (const float*)d_in[8];
    const float* Wi    = (const float*)d_in[9];
    const float* bi    = (const float*)d_in[10];
    float* out = (float*)d_out;

    unsigned char* ws = (unsigned char*)d_ws;
    unsigned short* Bt  = (unsigned short*)(ws + 0);        // 320*256*2 = 163,840 B
    unsigned short* Wst = (unsigned short*)(ws + 163840);   // 144*64*2  =  18,432 B

    k_prep<<<dim3(356), dim3(256), 0, stream>>>(Wi, Wr, Ws, Bt, Wst);
    k_fused<<<dim3(512), dim3(512), 0, stream>>>(
        x, Bt, Wst, bi, br, gamma, beta, mean, var, bs, out);
}

// Round 15
// 171.496 us; speedup vs baseline: 1.0232x; 1.0232x over previous
//
#include <hip/hip_runtime.h>

#define BN_EPS 1e-3f

typedef __attribute__((ext_vector_type(8))) short bf16x8;
typedef __attribute__((ext_vector_type(4))) float f32x4;

__device__ inline unsigned short f2b(float f) {
    unsigned int u = __float_as_uint(f);
    unsigned int r = (u + 0x7fffu + ((u >> 16) & 1u)) >> 16;
    return (unsigned short)r;
}
__device__ inline float b2f(unsigned short h) {
    return __uint_as_float(((unsigned int)h) << 16);
}
// packed RNE f32x2 -> bf16x2 (lo = a, hi = b) — single VALU instruction
__device__ inline unsigned int pk2(float a, float b) {
    unsigned int r;
    asm("v_cvt_pk_bf16_f32 %0, %1, %2" : "=v"(r) : "v"(a), "v"(b));
    return r;
}
// packed bf16x2 dot: D = x.lo*w.lo + x.hi*w.hi + acc   (single VALU instr)
__device__ inline float dot2bf(unsigned int x, unsigned int w, float acc) {
    float r;
    asm("v_dot2_f32_bf16 %0, %1, %2, %3" : "=v"(r) : "v"(x), "v"(w), "v"(acc));
    return r;
}

// ---------------------------------------------------------------------------
// k_prep: Bt[n][k] = bf16 of (n<256 ? Wi[k][n] : Wr[k][n-256])   [320,256]
//         Wst[n][k] = bf16 of Ws[k][n]                            [144,64]
// ---------------------------------------------------------------------------
__global__ void k_prep(const float* __restrict__ Wi, const float* __restrict__ Wr,
                       const float* __restrict__ Ws,
                       unsigned short* __restrict__ Bt, unsigned short* __restrict__ Wst) {
    int t = blockIdx.x * 256 + threadIdx.x;
    if (t < 320 * 256) {
        int n = t >> 8, k = t & 255;
        float v = (n < 256) ? Wi[k * 256 + n] : Wr[k * 64 + (n - 256)];
        Bt[t] = f2b(v);
    } else {
        int t2 = t - 320 * 256;
        if (t2 < 144 * 64) {
            int n = t2 >> 6, k = t2 & 63;
            Wst[t2] = f2b(Ws[k * 144 + n]);
        }
    }
}

// ---------------------------------------------------------------------------
// gather8: 8 outputs from one 72-element (36-dword) run of packed bf16.
// ---------------------------------------------------------------------------
__device__ __forceinline__ void gather8(const int* dwp, const unsigned* pkA,
                                        const unsigned* pkB, float w0f, float w8f,
                                        float* res) {
#pragma unroll
    for (int ff = 0; ff < 8; ++ff) {
        const int e0 = ff * 9;
        float a;
        if ((ff & 1) == 0) {
            const int d0 = e0 >> 1;
            a = __uint_as_float(((unsigned)dwp[d0 + 4]) << 16) * w8f;
            a = dot2bf((unsigned)dwp[d0 + 0], pkA[0], a);
            a = dot2bf((unsigned)dwp[d0 + 1], pkA[1], a);
            a = dot2bf((unsigned)dwp[d0 + 2], pkA[2], a);
            a = dot2bf((unsigned)dwp[d0 + 3], pkA[3], a);
        } else {
            const int di = e0 >> 1;          // element e0 sits in hi half
            const int d1 = di + 1;
            a = __uint_as_float(((unsigned)dwp[di]) & 0xffff0000u) * w0f;
            a = dot2bf((unsigned)dwp[d1 + 0], pkB[0], a);
            a = dot2bf((unsigned)dwp[d1 + 1], pkB[1], a);
            a = dot2bf((unsigned)dwp[d1 + 2], pkB[2], a);
            a = dot2bf((unsigned)dwp[d1 + 3], pkB[3], a);
        }
        res[ff] = a;
    }
}

// ---------------------------------------------------------------------------
// k_fused: one block = one 16x8 output tile (halo 18x10 = 180 px). 8 waves.
//   phase 1: 6 chunks of 32 halo rows, in-place LDS, 2-ahead staging,
//     ONE barrier per chunk. Chunk loop FULLY UNROLLED so the <180 bound
//     predicates and row addresses constant-fold (only chunk 5's upper rows
//     and chunk 3's staged write actually need masks).
//   phase 2: w = r @ Ws^T (+bs) on compacted 128 interior px -> WL.
//   phase 3: contiguous-run gather via v_dot2_f32_bf16 (packed bf16 pairs).
// LDS (u16): XI 180x264 | RS 180x72 | WL 128x144  = 157,824 B -> 1 block/CU.
// NOTE (r14): do NOT XOR-swizzle XI — XIP=264 already staggers row-start
// banks (stride 4, period 8); a (row&7)<<3 XOR raised conflicts 3.77M->9.4M.
// ---------------------------------------------------------------------------
#define XIP 264
#define RS_OFF (180 * XIP)            // 47520
#define RSP 72
#define WL_OFF (RS_OFF + 180 * RSP)   // 60480
#define SMN (WL_OFF + 128 * 144)      // 78912 u16 = 157,824 B

__global__ __launch_bounds__(512, 2) void k_fused(
    const float* __restrict__ x, const unsigned short* __restrict__ Bt,
    const unsigned short* __restrict__ Wst,
    const float* __restrict__ bi, const float* __restrict__ br,
    const float* __restrict__ gamma, const float* __restrict__ beta,
    const float* __restrict__ mean, const float* __restrict__ var,
    const float* __restrict__ bs, float* __restrict__ out)
{
    __shared__ __attribute__((aligned(16))) unsigned short sm[SMN];
    const int tid = threadIdx.x;
    const int bx = blockIdx.x;
    const int w0 = (bx & 7) * 16;
    const int h0 = ((bx >> 3) & 15) * 8;
    const int bb = bx >> 7;

    const int wv = tid >> 6;
    const int lane = tid & 63;
    const int col = lane & 15;
    const int quad = lane >> 4;

    // ---- load per-wave constants & register-resident B fragments ----
    const float bi_v0 = bi[(2 * wv) * 16 + col];
    const float bi_v1 = bi[(2 * wv + 1) * 16 + col];
    const int dcl = (wv & 3) * 16 + col;       // r-column (valid when wv<4)
    const float brd = br[dcl];
    const float md  = mean[dcl];
    const float sc  = gamma[dcl] * rsqrtf(var[dcl] + BN_EPS);
    const float btv = beta[dcl];

    bf16x8 bx0[8], bx1[8], brr[8];
    {
        const unsigned short* p0 = &Bt[((2 * wv) * 16 + col) * 256];
        const unsigned short* p1 = &Bt[((2 * wv + 1) * 16 + col) * 256];
#pragma unroll
        for (int kc = 0; kc < 8; ++kc) {
            bx0[kc] = *(const bf16x8*)&p0[kc * 32 + quad * 8];
            bx1[kc] = *(const bf16x8*)&p1[kc * 32 + quad * 8];
        }
        if (wv < 4) {
            const unsigned short* pr = &Bt[((16 + wv) * 16 + col) * 256];
#pragma unroll
            for (int kc = 0; kc < 8; ++kc)
                brr[kc] = *(const bf16x8*)&pr[kc * 32 + quad * 8];
        }
    }

    // ---- staging helpers ----
    const int chq = (tid & 15) * 4;

    // prologue: stage chunks 0 and 1 (rows 0..63, all < 180)
#pragma unroll
    for (int pc = 0; pc < 2; ++pc) {
        float4 vcur[4];
        const int hp = pc * 32 + (tid >> 4);
        int r = hp / 18, cc = hp - r * 18;
        int gh = h0 - 1 + r, gw = w0 - 1 + cc;
        bool ok = ((unsigned)gh < 128u) && ((unsigned)gw < 128u);
        if (ok) {
            const float* src = x + (((long long)(bb * 128 + gh)) * 128 + gw) * 256 + chq;
#pragma unroll
            for (int j = 0; j < 4; ++j) vcur[j] = *(const float4*)&src[j * 64];
        } else {
#pragma unroll
            for (int j = 0; j < 4; ++j) vcur[j] = (float4){0.f, 0.f, 0.f, 0.f};
        }
#pragma unroll
        for (int j = 0; j < 4; ++j) {
            uint2 pk;
            pk.x = pk2(vcur[j].x, vcur[j].y);
            pk.y = pk2(vcur[j].z, vcur[j].w);
            *(uint2*)&sm[hp * XIP + chq + j * 64] = pk;
        }
    }
    __syncthreads();

    // ---- chunk loop: ONE barrier per chunk, 2-ahead staging, UNROLLED ----
#pragma unroll
    for (int c = 0; c < 6; ++c) {
        float4 vn[4];
        int hp_n = 200;
        if (c < 4) {
            hp_n = (c + 2) * 32 + (tid >> 4);
            int r = hp_n / 18, cc = hp_n - r * 18;
            int gh = h0 - 1 + r, gw = w0 - 1 + cc;
            bool ok = (hp_n < 180) && ((unsigned)gh < 128u) && ((unsigned)gw < 128u);
            if (ok) {
                const float* src = x + (((long long)(bb * 128 + gh)) * 128 + gw) * 256 + chq;
#pragma unroll
                for (int j = 0; j < 4; ++j) vn[j] = *(const float4*)&src[j * 64];
            } else {
#pragma unroll
                for (int j = 0; j < 4; ++j) vn[j] = (float4){0.f, 0.f, 0.f, 0.f};
            }
        }

        // MFMA chunk c
        f32x4 a00 = {0.f,0.f,0.f,0.f}, a01 = a00, a10 = a00, a11 = a00;
        f32x4 ar0 = a00, ar1 = a00;
        {
            const int rowA0 = (c * 32 + col) * XIP;
            const int rowA1 = (c * 32 + 16 + col) * XIP;
#pragma unroll
            for (int kc = 0; kc < 8; ++kc) {
                const int kb = kc * 32 + quad * 8;
                bf16x8 a0 = *(const bf16x8*)&sm[rowA0 + kb];
                bf16x8 a1 = *(const bf16x8*)&sm[rowA1 + kb];
                a00 = __builtin_amdgcn_mfma_f32_16x16x32_bf16(a0, bx0[kc], a00, 0, 0, 0);
                a10 = __builtin_amdgcn_mfma_f32_16x16x32_bf16(a1, bx0[kc], a10, 0, 0, 0);
                a01 = __builtin_amdgcn_mfma_f32_16x16x32_bf16(a0, bx1[kc], a01, 0, 0, 0);
                a11 = __builtin_amdgcn_mfma_f32_16x16x32_bf16(a1, bx1[kc], a11, 0, 0, 0);
                if (wv < 4) {
                    ar0 = __builtin_amdgcn_mfma_f32_16x16x32_bf16(a0, brr[kc], ar0, 0, 0, 0);
                    ar1 = __builtin_amdgcn_mfma_f32_16x16x32_bf16(a1, brr[kc], ar1, 0, 0, 0);
                }
            }
        }
        __syncthreads();   // all waves' reads of rows_c done

        // epilogue chunk c: xi -> XI rows_c (in place), r -> RS rows_c
        // (for c<5 all rows < 180 — predicates constant-fold away)
        {
            const int n0 = (2 * wv) * 16 + col;
            const int n1 = (2 * wv + 1) * 16 + col;
            const int rb = c * 32 + quad * 4;
#pragma unroll
            for (int rg = 0; rg < 4; ++rg) {
                const int r0 = rb + rg, r1 = rb + 16 + rg;
                if (c < 5 || r0 < 180) {
                    const unsigned int u0 = pk2(a00[rg] + bi_v0, a01[rg] + bi_v1);
                    sm[r0 * XIP + n0] = (unsigned short)u0;
                    sm[r0 * XIP + n1] = (unsigned short)(u0 >> 16);
                }
                if (c < 5 || r1 < 180) {
                    const unsigned int u1 = pk2(a10[rg] + bi_v0, a11[rg] + bi_v1);
                    sm[r1 * XIP + n0] = (unsigned short)u1;
                    sm[r1 * XIP + n1] = (unsigned short)(u1 >> 16);
                }
            }
            if (wv < 4) {
#pragma unroll
                for (int rg = 0; rg < 4; ++rg) {
                    const int r0 = rb + rg, r1 = rb + 16 + rg;
                    if (c < 5 || r0 < 180) {
                        float v = (ar0[rg] + brd - md) * sc + btv;
                        sm[RS_OFF + r0 * RSP + dcl] = f2b(fmaxf(v, 0.f));
                    }
                    if (c < 5 || r1 < 180) {
                        float v = (ar1[rg] + brd - md) * sc + btv;
                        sm[RS_OFF + r1 * RSP + dcl] = f2b(fmaxf(v, 0.f));
                    }
                }
            }
        }

        // staged write chunk c+2 (rows disjoint; next read fenced by c+1 barrier)
        if (c < 4 && (c < 3 || hp_n < 180)) {
#pragma unroll
            for (int j = 0; j < 4; ++j) {
                uint2 pk;
                pk.x = pk2(vn[j].x, vn[j].y);
                pk.y = pk2(vn[j].z, vn[j].w);
                *(uint2*)&sm[hp_n * XIP + chq + j * 64] = pk;
            }
        }
    }
    __syncthreads();   // epi(5) RS/XI writes complete before phase 2

    // ---- phase 2: w = r @ Wst^T (+bs); wave wv -> m-tile wv ----
    {
        f32x4 wacc[9];
#pragma unroll
        for (int j = 0; j < 9; ++j) wacc[j] = (f32x4){0.f, 0.f, 0.f, 0.f};
        const int arow = (19 + wv * 18 + col) * RSP;
#pragma unroll
        for (int kc = 0; kc < 2; ++kc) {
            const int kb = kc * 32 + quad * 8;
            bf16x8 ra = *(const bf16x8*)&sm[RS_OFF + arow + kb];
#pragma unroll
            for (int j = 0; j < 9; ++j) {
                bf16x8 wb = *(const bf16x8*)&Wst[(j * 16 + col) * 64 + kb];
                wacc[j] = __builtin_amdgcn_mfma_f32_16x16x32_bf16(ra, wb, wacc[j], 0, 0, 0);
            }
        }
        const int prow = wv * 16 + quad * 4;
#pragma unroll
        for (int j = 0; j < 8; j += 2) {
            const int na = j * 16 + col;
            const int nb = na + 16;
            const float bva = bs[na];
            const float bvb = bs[nb];
#pragma unroll
            for (int rg = 0; rg < 4; ++rg) {
                const unsigned int u = pk2(wacc[j][rg] + bva, wacc[j + 1][rg] + bvb);
                sm[WL_OFF + (prow + rg) * 144 + na] = (unsigned short)u;
                sm[WL_OFF + (prow + rg) * 144 + nb] = (unsigned short)(u >> 16);
            }
        }
        {
            const int n = 8 * 16 + col;
            const float bv = bs[n];
#pragma unroll
            for (int rg = 0; rg < 4; ++rg)
                sm[WL_OFF + (prow + rg) * 144 + n] = f2b(wacc[8][rg] + bv);
        }
    }
    __syncthreads();

    // ---- phase 3: gather via packed bf16 dot2 ----
    {
        const int g = tid & 15;
        const int pb = tid >> 4;               // 0..31

        const int idx0 = g * 144;
        const int kp0  = idx0 >> 8;
        const int c0   = idx0 & 255;           // multiple of 16
        int len1 = 256 - c0; if (len1 > 144) len1 = 144;
        const int kp1  = kp0 + 1;
        const int koff0 = (kp0 / 3) * 18 + (kp0 % 3);
        const int koff1 = (kp1 <= 8) ? ((kp1 / 3) * 18 + (kp1 % 3)) : 0;

#pragma unroll
        for (int jj = 0; jj < 4; ++jj) {
            const int p = pb + 32 * jj;        // interior px 0..127
            const int phb = (p >> 4) * 18 + (p & 15);
            const int base0 = (phb + koff0) * XIP + c0;
            const int base1 = (phb + koff1) * XIP;

            // raw u16 weights -> packed bf16x2 operand sets
            unsigned wsv[9];
#pragma unroll
            for (int kk = 0; kk < 9; ++kk)
                wsv[kk] = sm[WL_OFF + p * 144 + g * 9 + kk];
            unsigned pkA[4], pkB[4];
#pragma unroll
            for (int k = 0; k < 4; ++k) {
                pkA[k] = (wsv[2 * k + 1] << 16) | wsv[2 * k];
                pkB[k] = (wsv[2 * k + 2] << 16) | wsv[2 * k + 1];
            }
            const float w0f = __uint_as_float(wsv[0] << 16);
            const float w8f = __uint_as_float(wsv[8] << 16);

            float res[16];
            {
                int4 xv[9];
#pragma unroll
                for (int i = 0; i < 9; ++i) {
                    const int e = i * 8;
                    const int addr = (e < len1) ? (base0 + e) : (base1 + (e - len1));
                    xv[i] = *(const int4*)&sm[addr];
                }
                gather8((const int*)xv, pkA, pkB, w0f, w8f, res);
            }
            {
                int4 xv[9];
#pragma unroll
                for (int i = 9; i < 18; ++i) {
                    const int e = i * 8;
                    const int addr = (e < len1) ? (base0 + e) : (base1 + (e - len1));
                    xv[i - 9] = *(const int4*)&sm[addr];
                }
                gather8((const int*)xv, pkA, pkB, w0f, w8f, res + 8);
            }

            const long long orow =
                (((long long)(bb * 128 + h0 + (p >> 4))) * 128 + (w0 + (p & 15))) * 256 + g * 16;
#pragma unroll
            for (int q = 0; q < 4; ++q) {
                float4 o = {res[q * 4 + 0], res[q * 4 + 1], res[q * 4 + 2], res[q * 4 + 3]};
                *(float4*)&out[orow + q * 4] = o;
            }
        }
    }
}

// ---------------------------------------------------------------------------
extern "C" void kernel_launch(void* const* d_in, const int* in_sizes, int n_in,
                              void* d_out, int out_size, void* d_ws, size_t ws_size,
                              hipStream_t stream) {
    const float* x     = (const float*)d_in[0];
    const float* Wr    = (const float*)d_in[1];
    const float* br    = (const float*)d_in[2];
    const float* gamma = (const float*)d_in[3];
    const float* beta  = (const float*)d_in[4];
    const float* mean  = (const float*)d_in[5];
    const float* var   = (const float*)d_in[6];
    const float* Ws    = (const float*)d_in[7];
    const float* bs    = (const float*)d_in[8];
    const float* Wi    = (const float*)d_in[9];
    const float* bi    = (const float*)d_in[10];
    float* out = (float*)d_out;

    unsigned char* ws = (unsigned char*)d_ws;
    unsigned short* Bt  = (unsigned short*)(ws + 0);        // 320*256*2 = 163,840 B
    unsigned short* Wst = (unsigned short*)(ws + 163840);   // 144*64*2  =  18,432 B

    k_prep<<<dim3(356), dim3(256), 0, stream>>>(Wi, Wr, Ws, Bt, Wst);
    k_fused<<<dim3(512), dim3(512), 0, stream>>>(
        x, Bt, Wst, bi, br, gamma, beta, mean, var, bs, out);
}